// Round 3
// baseline (1382.476 us; speedup 1.0000x reference)
//
#include <hip/hip_runtime.h>

// LightGCN forward, D=64, N=150k, NNZ=6M, 3 layers.
// CSR build (hist -> scan -> ILP-4 scatter) + gather SpMM (wave per row,
// lane == dim, paired int4 edge loads). acc pre-scaled by 0.25 at init so the
// final scale pass is fused away. Fallback to scatter-atomic SpMM if ws too
// small.

#define U_CNT 100000
#define I_CNT 50000
#define N_CNT 150000
#define DIM 64
#define NNZ_CNT 6000000
#define NSEL 4096

#define SCAN_BLK 256
#define SCAN_NBLK ((N_CNT + SCAN_BLK - 1) / SCAN_BLK)   // 586

// ---------------- shared small kernels ----------------

__global__ void init_kernel(const float* __restrict__ user_emb,
                            const float* __restrict__ item_emb,
                            float* __restrict__ cur,
                            float* __restrict__ acc) {
    const int total = N_CNT * DIM / 4;
    const int ubound = U_CNT * DIM / 4;
    const float4* ue = (const float4*)user_emb;
    const float4* ie = (const float4*)item_emb;
    float4* c4 = (float4*)cur;
    float4* a4 = (float4*)acc;
    for (int i = blockIdx.x * blockDim.x + threadIdx.x; i < total;
         i += gridDim.x * blockDim.x) {
        float4 v = (i < ubound) ? ue[i] : ie[i - ubound];
        c4[i] = v;
        float4 a = v;
        a.x *= 0.25f; a.y *= 0.25f; a.z *= 0.25f; a.w *= 0.25f;
        a4[i] = a;
    }
}

__global__ void gather_kernel(const float* __restrict__ final_emb,
                              const int* __restrict__ users,
                              const int* __restrict__ pos,
                              const int* __restrict__ neg,
                              float* __restrict__ out) {
    const int total = 3 * NSEL * (DIM / 4);
    const float4* f4 = (const float4*)final_emb;
    float4* o4 = (float4*)out;
    for (int i = blockIdx.x * blockDim.x + threadIdx.x; i < total;
         i += gridDim.x * blockDim.x) {
        const int rowi = i / (DIM / 4);
        const int d4 = i % (DIM / 4);
        int src;
        if (rowi < NSEL) {
            src = users[rowi];
        } else if (rowi < 2 * NSEL) {
            src = U_CNT + pos[rowi - NSEL];
        } else {
            src = U_CNT + neg[rowi - 2 * NSEL];
        }
        o4[i] = f4[src * (DIM / 4) + d4];
    }
}

// ---------------- CSR build ----------------

// 4 edges per thread per iteration via int4; 4 independent atomics in flight.
__global__ void hist_kernel(const int* __restrict__ row, int* __restrict__ cnt) {
    const int tid = blockIdx.x * blockDim.x + threadIdx.x;
    const int stride = gridDim.x * blockDim.x;
    const int4* r4 = (const int4*)row;
    for (int g = tid; g < NNZ_CNT / 4; g += stride) {
        const int4 r = r4[g];
        atomicAdd(&cnt[r.x], 1);
        atomicAdd(&cnt[r.y], 1);
        atomicAdd(&cnt[r.z], 1);
        atomicAdd(&cnt[r.w], 1);
    }
}

__global__ void scanA_kernel(const int* __restrict__ cnt,
                             int* __restrict__ off,
                             int* __restrict__ partials) {
    __shared__ int sdata[SCAN_BLK];
    const int tid = threadIdx.x;
    const int i = blockIdx.x * SCAN_BLK + tid;
    const int v = (i < N_CNT) ? cnt[i] : 0;
    sdata[tid] = v;
    __syncthreads();
    for (int d = 1; d < SCAN_BLK; d <<= 1) {
        int t = (tid >= d) ? sdata[tid - d] : 0;
        __syncthreads();
        sdata[tid] += t;
        __syncthreads();
    }
    if (i < N_CNT) off[i] = sdata[tid] - v;
    if (tid == SCAN_BLK - 1) partials[blockIdx.x] = sdata[tid];
}

__global__ void scanB_kernel(int* __restrict__ partials) {
    __shared__ int sdata[1024];
    const int tid = threadIdx.x;
    const int v = (tid < SCAN_NBLK) ? partials[tid] : 0;
    sdata[tid] = v;
    __syncthreads();
    for (int d = 1; d < 1024; d <<= 1) {
        int t = (tid >= d) ? sdata[tid - d] : 0;
        __syncthreads();
        sdata[tid] += t;
        __syncthreads();
    }
    if (tid < SCAN_NBLK) partials[tid] = sdata[tid] - v;
}

__global__ void scanC_kernel(int* __restrict__ off,
                             const int* __restrict__ partials,
                             int* __restrict__ cursor) {
    const int i = blockIdx.x * SCAN_BLK + threadIdx.x;
    if (i < N_CNT) {
        const int o = off[i] + partials[blockIdx.x];
        off[i] = o;
        cursor[i] = o;
    }
    if (i == 0) off[N_CNT] = NNZ_CNT;
}

// scatter: 4 edges/thread/iter with vectorized metadata loads; the 4
// atomicAdd round trips overlap (was the latency bottleneck at 1/thread).
__global__ void scatter_kernel(const float* __restrict__ val,
                               const int* __restrict__ row,
                               const int* __restrict__ col,
                               int* __restrict__ cursor,
                               int2* __restrict__ edges) {
    const int tid = blockIdx.x * blockDim.x + threadIdx.x;
    const int stride = gridDim.x * blockDim.x;
    const int4* r4 = (const int4*)row;
    const int4* c4 = (const int4*)col;
    const float4* v4 = (const float4*)val;
    for (int g = tid; g < NNZ_CNT / 4; g += stride) {
        const int4 r = r4[g];
        const int4 c = c4[g];
        const float4 v = v4[g];
        const int p0 = atomicAdd(&cursor[r.x], 1);
        const int p1 = atomicAdd(&cursor[r.y], 1);
        const int p2 = atomicAdd(&cursor[r.z], 1);
        const int p3 = atomicAdd(&cursor[r.w], 1);
        edges[p0] = make_int2(c.x, __float_as_int(v.x));
        edges[p1] = make_int2(c.y, __float_as_int(v.y));
        edges[p2] = make_int2(c.z, __float_as_int(v.z));
        edges[p3] = make_int2(c.w, __float_as_int(v.w));
    }
}

// ---------------- gather SpMM ----------------
// Wave per row, lane == dim. Paired int4 edge loads (2 edges / 16B), dual
// accumulators, unroll 2 -> 4 x-gathers outstanding.
__global__ void spmm_csr_kernel(const int2* __restrict__ edges,
                                const int* __restrict__ off,
                                const float* __restrict__ x,
                                float* __restrict__ y,
                                float* __restrict__ acc,
                                int write_y) {
    const int lane = threadIdx.x & 63;
    const int gw = (blockIdx.x * blockDim.x + threadIdx.x) >> 6;
    const int totalWaves = (gridDim.x * blockDim.x) >> 6;
    for (int r = gw; r < N_CNT; r += totalWaves) {
        const int beg = off[r];
        const int end = off[r + 1];
        float s0 = 0.f, s1 = 0.f;
        int e = beg;
        if (e < end && (e & 1)) {               // align to 16B pair boundary
            const int2 ev = edges[e];
            s0 += __int_as_float(ev.y) * x[(size_t)ev.x * DIM + lane];
            ++e;
        }
        #pragma unroll 2
        for (; e + 1 < end; e += 2) {
            const int4 ev2 = *reinterpret_cast<const int4*>(edges + e);
            s0 += __int_as_float(ev2.y) * x[(size_t)ev2.x * DIM + lane];
            s1 += __int_as_float(ev2.w) * x[(size_t)ev2.z * DIM + lane];
        }
        if (e < end) {
            const int2 ev = edges[e];
            s0 += __int_as_float(ev.y) * x[(size_t)ev.x * DIM + lane];
        }
        const float s = s0 + s1;
        const size_t oi = (size_t)r * DIM + lane;
        if (write_y) y[oi] = s;
        acc[oi] += 0.25f * s;
    }
}

// ---------------- fallback (scatter-atomic) ----------------

__global__ void spmm_atomic_kernel(const float* __restrict__ val,
                                   const int* __restrict__ row,
                                   const int* __restrict__ col,
                                   const float* __restrict__ x,
                                   float* __restrict__ y) {
    const int lane = threadIdx.x & 63;
    const int gw = (blockIdx.x * blockDim.x + threadIdx.x) >> 6;
    const int totalWaves = (gridDim.x * blockDim.x) >> 6;
    for (int base = gw * 64; base < NNZ_CNT; base += totalWaves * 64) {
        const int e = base + lane;
        const float v = val[e];
        const int r = row[e];
        const int c = col[e];
        #pragma unroll 8
        for (int k = 0; k < 64; ++k) {
            const float vk = __shfl(v, k);
            const int rk = __shfl(r, k);
            const int ck = __shfl(c, k);
            atomicAdd(&y[rk * DIM + lane], vk * x[ck * DIM + lane]);
        }
    }
}

__global__ void accum_scale_kernel(float* __restrict__ acc,
                                   const float* __restrict__ nxt,
                                   float wacc) {
    const int total = N_CNT * DIM / 4;
    float4* a4 = (float4*)acc;
    const float4* n4 = (const float4*)nxt;
    for (int i = blockIdx.x * blockDim.x + threadIdx.x; i < total;
         i += gridDim.x * blockDim.x) {
        float4 a = a4[i];
        const float4 n = n4[i];
        a.x += wacc * n.x; a.y += wacc * n.y; a.z += wacc * n.z; a.w += wacc * n.w;
        a4[i] = a;
    }
}

// ---------------- launch ----------------

extern "C" void kernel_launch(void* const* d_in, const int* in_sizes, int n_in,
                              void* d_out, int out_size, void* d_ws, size_t ws_size,
                              hipStream_t stream) {
    const float* user_emb  = (const float*)d_in[0];
    const float* item_emb  = (const float*)d_in[1];
    const float* adj_val   = (const float*)d_in[2];
    const int*   adj_row   = (const int*)d_in[3];
    const int*   adj_col   = (const int*)d_in[4];
    const int*   users     = (const int*)d_in[5];
    const int*   pos_items = (const int*)d_in[6];
    const int*   neg_items = (const int*)d_in[7];
    // d_in[8] = num_layers, fixed at 3 (device scalar; host read would break
    // graph capture).

    float* out       = (float*)d_out;
    float* out_sel   = out;
    float* final_emb = out + (size_t)3 * NSEL * DIM;
    float* acc       = final_emb;

    const size_t NB = (size_t)N_CNT * DIM * sizeof(float);   // 38,400,000
    char* ws = (char*)d_ws;
    float* bufA = (float*)(ws + 0);
    float* bufB = (float*)(ws + NB);

    const size_t offE   = 2 * NB;
    const size_t offOff = offE + (size_t)NNZ_CNT * 8;
    const size_t offCur = offOff + 600016;
    const size_t offCnt = offCur + 600000;
    const size_t offP   = offCnt + 600000;
    const size_t needed = offP + 4096;

    init_kernel<<<2048, 256, 0, stream>>>(user_emb, item_emb, bufA, acc);

    if (ws_size >= needed) {
        int2* edges   = (int2*)(ws + offE);
        int*  offp    = (int*)(ws + offOff);
        int*  cursor  = (int*)(ws + offCur);
        int*  cnt     = (int*)(ws + offCnt);
        int*  partial = (int*)(ws + offP);

        hipMemsetAsync(cnt, 0, N_CNT * sizeof(int), stream);
        hist_kernel<<<2048, 256, 0, stream>>>(adj_row, cnt);
        scanA_kernel<<<SCAN_NBLK, SCAN_BLK, 0, stream>>>(cnt, offp, partial);
        scanB_kernel<<<1, 1024, 0, stream>>>(partial);
        scanC_kernel<<<SCAN_NBLK, SCAN_BLK, 0, stream>>>(offp, partial, cursor);
        scatter_kernel<<<2048, 256, 0, stream>>>(adj_val, adj_row, adj_col,
                                                 cursor, edges);

        float* cur = bufA;
        float* nxt = bufB;
        for (int l = 0; l < 3; ++l) {
            spmm_csr_kernel<<<2048, 256, 0, stream>>>(edges, offp, cur, nxt, acc,
                                                      (l < 2) ? 1 : 0);
            float* t = cur; cur = nxt; nxt = t;
        }
    } else {
        float* cur = bufA;
        float* nxt = bufB;
        for (int l = 0; l < 3; ++l) {
            hipMemsetAsync(nxt, 0, NB, stream);
            spmm_atomic_kernel<<<2048, 256, 0, stream>>>(adj_val, adj_row,
                                                         adj_col, cur, nxt);
            accum_scale_kernel<<<2048, 256, 0, stream>>>(acc, nxt, 0.25f);
            float* t = cur; cur = nxt; nxt = t;
        }
    }

    gather_kernel<<<768, 256, 0, stream>>>(final_emb, users, pos_items,
                                           neg_items, out_sel);
}